// Round 1
// baseline (447.943 us; speedup 1.0000x reference)
//
#include <hip/hip_runtime.h>
#include <math.h>

#define IN_F 64
#define OUT_F 32
#define NEG_SLOPE 0.2f

// Float atomic max via monotone integer mapping (valid for non-NaN floats).
__device__ __forceinline__ void atomicMaxFloat(float* addr, float val) {
    if (val >= 0.0f) {
        atomicMax((int*)addr, __float_as_int(val));
    } else {
        atomicMin((unsigned int*)addr, __float_as_uint(val));
    }
}

// Stage 1: h = x @ W  (N x 64 @ 64 x 32), plus a_src/a_dst per-node logits,
// self-loop logit, and segment-max init.
// 256 threads/block = 8 nodes/block, 32 lanes per node (lane = output channel).
__global__ void k_proj(const float* __restrict__ x, const float* __restrict__ W,
                       const float* __restrict__ att_src, const float* __restrict__ att_dst,
                       float* __restrict__ h, float* __restrict__ asrc,
                       float* __restrict__ adst, float* __restrict__ selfe,
                       float* __restrict__ maxv, int N) {
    __shared__ float Ws[IN_F * OUT_F];   // 8 KB
    __shared__ float xs[8][IN_F];        // 2 KB
    const int tid = threadIdx.x;
    for (int i = tid; i < IN_F * OUT_F; i += 256) Ws[i] = W[i];
    const int base = blockIdx.x * 8;
    for (int i = tid; i < 8 * IN_F; i += 256) {
        int node = base + i / IN_F;
        xs[0][i] = (node < N) ? x[(size_t)base * IN_F + i] : 0.0f;
    }
    __syncthreads();

    const int ln = tid >> 5;     // local node 0..7
    const int c  = tid & 31;     // output channel
    const int node = base + ln;
    float sum = 0.0f;
    #pragma unroll
    for (int k = 0; k < IN_F; ++k) sum += xs[ln][k] * Ws[k * OUT_F + c];

    if (node < N) {
        h[(size_t)node * OUT_F + c] = sum;
        float vs = sum * att_src[c];
        float vd = sum * att_dst[c];
        #pragma unroll
        for (int m = 16; m >= 1; m >>= 1) {
            vs += __shfl_xor(vs, m);
            vd += __shfl_xor(vd, m);
        }
        if (c == 0) {
            asrc[node] = vs;
            adst[node] = vd;
            float e = vs + vd;
            e = (e > 0.0f) ? e : NEG_SLOPE * e;
            selfe[node] = e;   // self-loop logit
            maxv[node]  = e;   // segment-max seeded with self loop
        }
    }
}

// Stage 2: per-edge leaky-relu logit + atomic segment max over dst.
__global__ void k_edge_logits(const int* __restrict__ src, const int* __restrict__ dst,
                              const float* __restrict__ asrc, const float* __restrict__ adst,
                              float* __restrict__ ev, float* __restrict__ maxv, int E) {
    int e = blockIdx.x * 256 + threadIdx.x;
    if (e >= E) return;
    int s = src[e];
    int d = dst[e];
    float v = asrc[s] + adst[d];
    v = (v > 0.0f) ? v : NEG_SLOPE * v;
    ev[e] = v;
    atomicMaxFloat(&maxv[d], v);
}

// Stage 3: denom initialized with the self-loop contribution.
__global__ void k_denom_init(const float* __restrict__ selfe, const float* __restrict__ maxv,
                             float* __restrict__ denom, int N) {
    int i = blockIdx.x * 256 + threadIdx.x;
    if (i < N) denom[i] = expf(selfe[i] - maxv[i]);
}

// Stage 4: per-edge exp + atomic segment sum.
__global__ void k_edge_exp(const int* __restrict__ dst, float* __restrict__ ev,
                           const float* __restrict__ maxv, float* __restrict__ denom, int E) {
    int e = blockIdx.x * 256 + threadIdx.x;
    if (e >= E) return;
    int d = dst[e];
    float ex = expf(ev[e] - maxv[d]);
    ev[e] = ex;
    atomicAdd(&denom[d], ex);
}

// Stage 5: weighted scatter-add. 32 lanes per edge, lane = channel.
__global__ void k_scatter(const int* __restrict__ src, const int* __restrict__ dst,
                          const float* __restrict__ ev, const float* __restrict__ denom,
                          const float* __restrict__ h, float* __restrict__ out, int E) {
    int t = blockIdx.x * 256 + threadIdx.x;
    int e = t >> 5;
    int c = t & 31;
    if (e >= E) return;
    int s = src[e];
    int d = dst[e];
    float alpha = ev[e] / denom[d];
    atomicAdd(&out[(size_t)d * OUT_F + c], h[(size_t)s * OUT_F + c] * alpha);
}

// Stage 6: add self-loop term + bias, relu.
__global__ void k_final(float* __restrict__ out, const float* __restrict__ h,
                        const float* __restrict__ selfe, const float* __restrict__ maxv,
                        const float* __restrict__ denom, const float* __restrict__ bias, int N) {
    int t = blockIdx.x * 256 + threadIdx.x;
    int n = t >> 5;
    int c = t & 31;
    if (n >= N) return;
    float alpha = expf(selfe[n] - maxv[n]) / denom[n];
    size_t idx = (size_t)n * OUT_F + c;
    float v = out[idx] + h[idx] * alpha + bias[c];
    out[idx] = (v > 0.0f) ? v : 0.0f;
}

extern "C" void kernel_launch(void* const* d_in, const int* in_sizes, int n_in,
                              void* d_out, int out_size, void* d_ws, size_t ws_size,
                              hipStream_t stream) {
    const float* x        = (const float*)d_in[0];
    const int*   eidx     = (const int*)d_in[1];   // [2, E] flat, int32 per harness contract
    const float* W        = (const float*)d_in[2];
    const float* att_src  = (const float*)d_in[3];
    const float* att_dst  = (const float*)d_in[4];
    const float* bias     = (const float*)d_in[5];
    float* out = (float*)d_out;

    const int N = in_sizes[0] / IN_F;
    const int E = in_sizes[1] / 2;
    const int* src = eidx;
    const int* dst = eidx + E;

    // Workspace layout (floats)
    float* ws    = (float*)d_ws;
    float* h     = ws;                       // N*32
    float* asrc  = h + (size_t)N * OUT_F;    // N
    float* adst  = asrc + N;                 // N
    float* selfe = adst + N;                 // N
    float* maxv  = selfe + N;                // N
    float* denom = maxv + N;                 // N
    float* ev    = denom + N;                // E

    // Zero the accumulator output (harness poisons it with 0xAA).
    hipMemsetAsync(out, 0, (size_t)out_size * sizeof(float), stream);

    const int nodeBlocks8 = (N + 7) / 8;          // 8 nodes per 256-thread block
    const int nodeBlocks  = (N + 255) / 256;
    const int edgeBlocks  = (E + 255) / 256;
    const int scatBlocks  = (E + 7) / 8;          // 8 edges per 256-thread block
    const int nodeCBlocks = ((size_t)N * OUT_F + 255) / 256;

    k_proj<<<nodeBlocks8, 256, 0, stream>>>(x, W, att_src, att_dst, h, asrc, adst, selfe, maxv, N);
    k_edge_logits<<<edgeBlocks, 256, 0, stream>>>(src, dst, asrc, adst, ev, maxv, E);
    k_denom_init<<<nodeBlocks, 256, 0, stream>>>(selfe, maxv, denom, N);
    k_edge_exp<<<edgeBlocks, 256, 0, stream>>>(dst, ev, maxv, denom, E);
    k_scatter<<<scatBlocks, 256, 0, stream>>>(src, dst, ev, denom, h, out, E);
    k_final<<<nodeCBlocks, 256, 0, stream>>>(out, h, selfe, maxv, denom, bias, N);
}

// Round 3
// 397.148 us; speedup vs baseline: 1.1279x; 1.1279x over previous
//
#include <hip/hip_runtime.h>
#include <math.h>

#define IN_F 64
#define OUT_F 32
#define NEG_SLOPE 0.2f

__device__ __forceinline__ float leaky(float v) {
    return (v > 0.0f) ? v : NEG_SLOPE * v;
}

// Stage 1: h = x @ W  (N x 64 @ 64 x 32), plus a_src/a_dst per-node logits.
// 256 threads/block = 8 nodes/block, 32 lanes per node (lane = output channel).
__global__ void k_proj(const float* __restrict__ x, const float* __restrict__ W,
                       const float* __restrict__ att_src, const float* __restrict__ att_dst,
                       float* __restrict__ h, float* __restrict__ asrc,
                       float* __restrict__ adst, int N) {
    __shared__ float Ws[IN_F * OUT_F];   // 8 KB
    __shared__ float xs[8 * IN_F];       // 2 KB
    const int tid = threadIdx.x;
    for (int i = tid; i < IN_F * OUT_F; i += 256) Ws[i] = W[i];
    const int base = blockIdx.x * 8;
    for (int i = tid; i < 8 * IN_F; i += 256) {
        int node = base + i / IN_F;
        xs[i] = (node < N) ? x[(size_t)base * IN_F + i] : 0.0f;
    }
    __syncthreads();

    const int ln = tid >> 5;     // local node 0..7
    const int c  = tid & 31;     // output channel
    const int node = base + ln;
    float sum = 0.0f;
    #pragma unroll
    for (int k = 0; k < IN_F; ++k) sum += xs[ln * IN_F + k] * Ws[k * OUT_F + c];

    if (node < N) {
        h[(size_t)node * OUT_F + c] = sum;
        float vs = sum * att_src[c];
        float vd = sum * att_dst[c];
        #pragma unroll
        for (int m = 16; m >= 1; m >>= 1) {
            vs += __shfl_xor(vs, m);
            vd += __shfl_xor(vd, m);
        }
        if (c == 0) {
            asrc[node] = vs;
            adst[node] = vd;
        }
    }
}

// Stage 2: histogram of destination degrees.
__global__ void k_hist(const int* __restrict__ dst, int* __restrict__ cnt, int E) {
    int e = blockIdx.x * 256 + threadIdx.x;
    if (e < E) atomicAdd(&cnt[dst[e]], 1);
}

// Stage 3a: per-256-block exclusive scan of cnt -> offs (in-block part) + block sums.
__global__ void k_scan1(const int* __restrict__ cnt, int* __restrict__ offs,
                        int* __restrict__ bsum, int N) {
    const int tid = threadIdx.x;            // 256
    const int i = blockIdx.x * 256 + tid;
    int v = (i < N) ? cnt[i] : 0;
    const int orig = v;
    const int lane = tid & 63;
    #pragma unroll
    for (int m = 1; m < 64; m <<= 1) {
        int u = __shfl_up(v, m);
        if (lane >= m) v += u;
    }
    __shared__ int wt[4];
    if (lane == 63) wt[tid >> 6] = v;
    __syncthreads();
    if (tid < 64) {
        int w = (tid < 4) ? wt[tid] : 0;
        #pragma unroll
        for (int m = 1; m < 4; m <<= 1) {
            int u = __shfl_up(w, m);
            if (tid >= m) w += u;
        }
        if (tid < 4) wt[tid] = w;   // inclusive wave totals
    }
    __syncthreads();
    if (tid >= 64) v += wt[(tid >> 6) - 1];
    if (i < N) offs[i] = v - orig;          // exclusive within block
    if (tid == 255) bsum[blockIdx.x] = v;   // block total
}

// Stage 3b: single-block exclusive scan of block sums (nb <= 512).
__global__ void k_scan2(int* __restrict__ bsum, int nb) {
    const int tid = threadIdx.x;            // 512
    int v = (tid < nb) ? bsum[tid] : 0;
    const int orig = v;
    const int lane = tid & 63;
    #pragma unroll
    for (int m = 1; m < 64; m <<= 1) {
        int u = __shfl_up(v, m);
        if (lane >= m) v += u;
    }
    __shared__ int wt[8];
    if (lane == 63) wt[tid >> 6] = v;
    __syncthreads();
    if (tid < 64) {
        int w = (tid < 8) ? wt[tid] : 0;
        #pragma unroll
        for (int m = 1; m < 8; m <<= 1) {
            int u = __shfl_up(w, m);
            if (tid >= m) w += u;
        }
        if (tid < 8) wt[tid] = w;
    }
    __syncthreads();
    if (tid >= 64) v += wt[(tid >> 6) - 1];
    if (tid < nb) bsum[tid] = v - orig;     // exclusive
}

// Stage 3c: add block offsets; duplicate into the mutable bucket cursor.
__global__ void k_scan3(int* __restrict__ offs, const int* __restrict__ bsum,
                        int* __restrict__ cursor, int N) {
    int i = blockIdx.x * 256 + threadIdx.x;
    if (i < N) {
        int v = offs[i] + bsum[i >> 8];
        offs[i] = v;
        cursor[i] = v;
    }
}

// Stage 4: bucket edges by destination: col[] = source ids grouped by dst.
__global__ void k_bucket(const int* __restrict__ src, const int* __restrict__ dst,
                         int* __restrict__ cursor, int* __restrict__ col, int E) {
    int e = blockIdx.x * 256 + threadIdx.x;
    if (e >= E) return;
    int d = dst[e];
    int p = atomicAdd(&cursor[d], 1);
    col[p] = src[e];
}

// Stage 5: fused online-softmax gather. 32 lanes per destination node, lane=channel.
// Self loop seeds (m=e_self, l=1, acc=h[n]); edges merged online; epilogue fused.
__global__ void k_gather(const int* __restrict__ col, const int* __restrict__ offs,
                         const int* __restrict__ cnt, const float* __restrict__ asrc,
                         const float* __restrict__ adst, const float* __restrict__ h,
                         const float* __restrict__ bias, float* __restrict__ out, int N) {
    int t = blockIdx.x * 256 + threadIdx.x;
    int n = t >> 5;
    int c = t & 31;
    if (n >= N) return;
    const float adst_n = adst[n];
    float m = leaky(asrc[n] + adst_n);      // self-loop logit
    float l = 1.0f;
    float acc = h[(size_t)n * OUT_F + c];
    const int off = offs[n];
    const int deg = cnt[n];
    for (int i = 0; i < deg; ++i) {
        int s = col[off + i];               // broadcast load (all 32 lanes same addr)
        float e = leaky(asrc[s] + adst_n);  // broadcast load of asrc[s]
        float nm = fmaxf(m, e);
        float scale = __expf(m - nm);
        float p = __expf(e - nm);
        l = l * scale + p;
        acc = acc * scale + p * h[(size_t)s * OUT_F + c];  // coalesced 128B row
        m = nm;
    }
    float v = acc / l + bias[c];
    out[(size_t)n * OUT_F + c] = fmaxf(v, 0.0f);
}

extern "C" void kernel_launch(void* const* d_in, const int* in_sizes, int n_in,
                              void* d_out, int out_size, void* d_ws, size_t ws_size,
                              hipStream_t stream) {
    const float* x        = (const float*)d_in[0];
    const int*   eidx     = (const int*)d_in[1];   // [2, E] flat int32
    const float* W        = (const float*)d_in[2];
    const float* att_src  = (const float*)d_in[3];
    const float* att_dst  = (const float*)d_in[4];
    const float* bias     = (const float*)d_in[5];
    float* out = (float*)d_out;

    const int N = in_sizes[0] / IN_F;
    const int E = in_sizes[1] / 2;
    const int* src = eidx;
    const int* dst = eidx + E;

    // Workspace layout (all 4-byte elements), ~21.2 MB total:
    float* ws    = (float*)d_ws;
    float* h     = ws;                         // N*32
    float* asrc  = h + (size_t)N * OUT_F;      // N
    float* adst  = asrc + N;                   // N
    int* cnt     = (int*)(adst + N);           // N
    int* offs    = cnt + N;                    // N (scanned in place)
    int* cursor  = offs + N;                   // N
    int* bsum    = cursor + N;                 // 512
    int* col     = bsum + 512;                 // E

    const int nodeBlocks8 = (N + 7) / 8;
    const int nodeBlocks  = (N + 255) / 256;   // also the scan1 grid (must be <= 512)
    const int edgeBlocks  = (E + 255) / 256;
    const int gatherBlocks = ((size_t)N * 32 + 255) / 256;  // N*32 threads (32 lanes/node)

    hipMemsetAsync(cnt, 0, (size_t)N * sizeof(int), stream);

    k_proj<<<nodeBlocks8, 256, 0, stream>>>(x, W, att_src, att_dst, h, asrc, adst, N);
    k_hist<<<edgeBlocks, 256, 0, stream>>>(dst, cnt, E);
    k_scan1<<<nodeBlocks, 256, 0, stream>>>(cnt, offs, bsum, N);
    k_scan2<<<1, 512, 0, stream>>>(bsum, nodeBlocks);
    k_scan3<<<nodeBlocks, 256, 0, stream>>>(offs, bsum, cursor, N);
    k_bucket<<<edgeBlocks, 256, 0, stream>>>(src, dst, cursor, col, E);
    k_gather<<<gatherBlocks, 256, 0, stream>>>(col, offs, cnt, asrc, adst, h, bias, out, N);
}